// Round 11
// baseline (214.860 us; speedup 1.0000x reference)
//
#include <hip/hip_runtime.h>
#include <hip/hip_bf16.h>

// Problem constants
#define M_DIM 2048
#define K_DIM 50000
#define N_DIM 256
#define L_PATH 32
// GEMM tiling
#define BMt 128
#define BNt 256
#define BKt 64
#define TOTAL_KSTEPS 782      // ceil(50000/64)
#define MTILES 16             // 2048/128

typedef __bf16 bf16x8 __attribute__((ext_vector_type(8)));
typedef __bf16 bf16x4 __attribute__((ext_vector_type(4)));
typedef float f32x4 __attribute__((ext_vector_type(4)));
typedef float fx4 __attribute__((ext_vector_type(4)));

// x = A (2048x50000) * W^T (W is 256x50000), split-K (runtime 16 or 32).
// R7's proven loop (single 48-VGPR stage set, counted vmcnt, raw barriers)
// shrunk to 64KB LDS (A double-buffered, W SINGLE-buffered) so 2 blocks fit
// per CU. Co-resident blocks differ only in ksp -> disjoint A and W slabs ->
// ZERO traffic duplication (R8/R10 failed because BM/BN splits duplicate an
// operand). The partner block fills the per-step drain + barrier stalls that
// made R7's lockstep cost ~5.7Kcyc/step vs its ~2-3.6Kcyc memory floor.
// W single-buffer needs a barrier after compute (readers done) before packW;
// second barrier after lgkmcnt(0) publishes the writes. Loads for t+2 are
// issued between them and stay in flight across both (never vmcnt(0)).
__global__ __launch_bounds__(512)
void gemm_bf16_splitk(const float* __restrict__ A, const float* __restrict__ W,
                      float* __restrict__ outp, int kmask, int kshift, int use_atomic)
{
  // Swizzled bf16 LDS tiles: (row, col) at row*BKt + XOR on 8-col/16B granule
  __shared__ __align__(16) unsigned short sA[2][BMt * BKt];   // 2 x 16 KB
  __shared__ __align__(16) unsigned short sW[BNt * BKt];      // 32 KB  (total 64 KB)

  int bid = blockIdx.x;
  int ksp = bid & kmask;             // consecutive bids = consecutive ksp ->
  int mtile = bid >> kshift;         // same-ksp blocks spread round-robin, and
                                     // CU-pairs (b, b+256) share mtile, differ ksp.
  int m0 = mtile * BMt;
  // balanced K ranges: s0 = floor(782*ksp/nsplit)
  int s0 = (TOTAL_KSTEPS * ksp) >> kshift;
  int s1 = (TOTAL_KSTEPS * (ksp + 1)) >> kshift;

  int tid = threadIdx.x;
  int wid = tid >> 6, lane = tid & 63;
  int wm = wid >> 2, wn = wid & 3;          // wave grid 2 x 4, each wave 64x64
  int l15 = lane & 15, l4 = lane >> 4;

  // Coalesced staging: 16 lanes x 16B cover one 64-col row chunk (256 B).
  int rowt = tid >> 4;   // 0..31
  int chk  = tid & 15;   // 16B chunk (4 fp32 cols)
  const float* Ab = A + (size_t)(m0 + rowt) * K_DIM + chk * 4;
  const float* Wb = W + (size_t)rowt * K_DIM + chk * 4;

  int offA[4], offW[8];
#pragma unroll
  for (int i = 0; i < 4; ++i) {
    int r = i * 32 + rowt;
    offA[i] = r * BKt + ((((chk >> 1) ^ (r & 7)) << 3) + (chk & 1) * 4);
  }
#pragma unroll
  for (int i = 0; i < 8; ++i) {
    int r = i * 32 + rowt;
    offW[i] = r * BKt + ((((chk >> 1) ^ (r & 7)) << 3) + (chk & 1) * 4);
  }

  // SINGLE stage set: 12 x fx4 = 48 VGPR (R3/R4/R6: two sets spill at the
  // 128-VGPR allocator cap for 512-thread blocks).
  fx4 ra[4], rw[8];

  auto issue = [&](int s) {
    size_t kb = (size_t)s * BKt;
    const float* ap = Ab + kb;
    const float* wp = Wb + kb;
    int k = s * BKt + chk * 4;
    if (k + 4 <= K_DIM) {
#pragma unroll
      for (int i = 0; i < 4; ++i) ra[i] = *reinterpret_cast<const fx4*>(ap + (size_t)i * 32 * K_DIM);
#pragma unroll
      for (int i = 0; i < 8; ++i) rw[i] = *reinterpret_cast<const fx4*>(wp + (size_t)i * 32 * K_DIM);
    } else {
#pragma unroll
      for (int i = 0; i < 4; ++i) {
        fx4 f;
#pragma unroll
        for (int e = 0; e < 4; ++e) f[e] = (k + e < K_DIM) ? ap[(size_t)i * 32 * K_DIM + e] : 0.f;
        ra[i] = f;
      }
#pragma unroll
      for (int i = 0; i < 8; ++i) {
        fx4 f;
#pragma unroll
        for (int e = 0; e < 4; ++e) f[e] = (k + e < K_DIM) ? wp[(size_t)i * 32 * K_DIM + e] : 0.f;
        rw[i] = f;
      }
    }
  };

  // fp32 -> bf16 casts (v_cvt_pk_bf16_f32, RTNE); counted vmcnt per write.
  auto packW = [&]() {
#pragma unroll
    for (int i = 0; i < 8; ++i) {
      bf16x4 h;
      h[0] = (__bf16)rw[i][0]; h[1] = (__bf16)rw[i][1];
      h[2] = (__bf16)rw[i][2]; h[3] = (__bf16)rw[i][3];
      *reinterpret_cast<bf16x4*>(&sW[offW[i]]) = h;
    }
  };
  auto packA = [&](int p) {
#pragma unroll
    for (int i = 0; i < 4; ++i) {
      bf16x4 h;
      h[0] = (__bf16)ra[i][0]; h[1] = (__bf16)ra[i][1];
      h[2] = (__bf16)ra[i][2]; h[3] = (__bf16)ra[i][3];
      *reinterpret_cast<bf16x4*>(&sA[p][offA[i]]) = h;
    }
  };

  f32x4 acc[4][4] = {};

  auto compute = [&](int p) {
#pragma unroll
    for (int kk = 0; kk < 2; ++kk) {
      bf16x8 afr[4], bfr[4];
      int c = kk * 32 + l4 * 8;
#pragma unroll
      for (int mf = 0; mf < 4; ++mf) {
        int r = wm * 64 + mf * 16 + l15;
        afr[mf] = *reinterpret_cast<const bf16x8*>(&sA[p][r * BKt + (c ^ ((r & 7) << 3))]);
      }
#pragma unroll
      for (int nf = 0; nf < 4; ++nf) {
        int r = wn * 64 + nf * 16 + l15;
        bfr[nf] = *reinterpret_cast<const bf16x8*>(&sW[r * BKt + (c ^ ((r & 7) << 3))]);
      }
#pragma unroll
      for (int mf = 0; mf < 4; ++mf)
#pragma unroll
        for (int nf = 0; nf < 4; ++nf)
          acc[mf][nf] = __builtin_amdgcn_mfma_f32_16x16x32_bf16(afr[mf], bfr[nf], acc[mf][nf], 0, 0, 0);
    }
  };

  // Prologue: stage tile s0 (A->sA[0], W->sW); tile s0+1 loads left in flight.
  issue(s0);
  packW();
  packA(0);
  if (s0 + 1 < s1) issue(s0 + 1);
  asm volatile("s_waitcnt lgkmcnt(0)" ::: "memory");
  __builtin_amdgcn_s_barrier();

  int p = 0;
  for (int t = s0; t < s1; ++t) {
    compute(p);                      // reads sA[p], sW; in-flight loads drain behind
    if (t + 1 < s1) {
      __builtin_amdgcn_s_barrier();  // all waves done reading sW (no drain: raw)
      packW();                       // counted vmcnt: waits tile t+1 loads only
      packA(p ^ 1);
      if (t + 2 < s1) issue(t + 2);  // crosses the next barrier in flight
      asm volatile("s_waitcnt lgkmcnt(0)" ::: "memory");
      __builtin_amdgcn_s_barrier();  // publish sW/sA[p^1]
    }
    p ^= 1;
  }

  // epilogue: C/D layout col = lane&15, row = (lane>>4)*4 + j
  if (use_atomic) {
#pragma unroll
    for (int mf = 0; mf < 4; ++mf)
#pragma unroll
      for (int nf = 0; nf < 4; ++nf)
#pragma unroll
        for (int j = 0; j < 4; ++j) {
          int row = m0 + wm * 64 + mf * 16 + l4 * 4 + j;
          int col = wn * 64 + nf * 16 + l15;
          atomicAdd(&outp[(size_t)row * N_DIM + col], acc[mf][nf][j]);
        }
  } else {
    float* part = outp + (size_t)ksp * (M_DIM * N_DIM);
#pragma unroll
    for (int mf = 0; mf < 4; ++mf)
#pragma unroll
      for (int nf = 0; nf < 4; ++nf)
#pragma unroll
        for (int j = 0; j < 4; ++j) {
          int row = m0 + wm * 64 + mf * 16 + l4 * 4 + j;
          int col = wn * 64 + nf * 16 + l15;
          part[(size_t)row * N_DIM + col] = acc[mf][nf][j];
        }
  }
}

// ---------------------------------------------------------------------------
// One block per sample: reduce split-K partials, gather path vecs, dot, BCE,
// atomically accumulate batch mean into out[0] (memset to 0 beforehand).
__global__ __launch_bounds__(256)
void loss_kernel(const float* __restrict__ part, int nparts,
                 const float* __restrict__ cls_w,
                 const int* __restrict__ nodes, const int* __restrict__ codes,
                 const int* __restrict__ lens, float* __restrict__ out)
{
  int i = blockIdx.x;
  int tid = threadIdx.x;
  __shared__ float s_x[N_DIM];
  {
    float s = 0.f;
    for (int k = 0; k < nparts; ++k)
      s += part[(size_t)k * (M_DIM * N_DIM) + (size_t)i * N_DIM + tid];
    s_x[tid] = s;
  }
  __syncthreads();

  int wid = tid >> 6, lane = tid & 63;
  __shared__ float s_logit[L_PATH];
  fx4 xv = *reinterpret_cast<const fx4*>(&s_x[lane * 4]);
#pragma unroll
  for (int j = 0; j < 8; ++j) {
    int pos = wid * 8 + j;
    int node = nodes[i * L_PATH + pos];
    fx4 cv = *reinterpret_cast<const fx4*>(&cls_w[(size_t)node * N_DIM + lane * 4]);
    float d = xv[0] * cv[0] + xv[1] * cv[1] + xv[2] * cv[2] + xv[3] * cv[3];
#pragma unroll
    for (int s = 32; s > 0; s >>= 1) d += __shfl_xor(d, s);
    if (lane == 0) s_logit[pos] = d;
  }
  __syncthreads();
  if (wid == 0) {
    int len = lens[i];
    int lenc = len < 1 ? 1 : len;
    float v = 0.f;
    if (lane < L_PATH && lane < lenc) {
      float z = s_logit[lane];
      float y = (float)codes[i * L_PATH + lane];
      v = fmaxf(z, 0.f) - z * y + log1pf(expf(-fabsf(z)));
    }
#pragma unroll
    for (int s = 32; s > 0; s >>= 1) v += __shfl_xor(v, s);
    if (lane == 0) atomicAdd(out, v / (float)lenc * (1.0f / (float)M_DIM));
  }
}

extern "C" void kernel_launch(void* const* d_in, const int* in_sizes, int n_in,
                              void* d_out, int out_size, void* d_ws, size_t ws_size,
                              hipStream_t stream) {
  const float* A     = (const float*)d_in[0];   // inputs_vector [2048, 50000]
  const float* W     = (const float*)d_in[1];   // W [256, 50000]
  const float* cls_w = (const float*)d_in[2];   // [49999, 256]
  const int* nodes   = (const int*)d_in[3];     // [2048, 32]
  const int* codes   = (const int*)d_in[4];     // [2048, 32]
  const int* lens    = (const int*)d_in[5];     // [2048]
  float* out = (float*)d_out;

  char* ws = (char*)d_ws;
  const size_t XBYTES = (size_t)M_DIM * N_DIM * sizeof(float);   // 2 MB
  float* x        = (float*)(ws + (size_t)(64u << 10));          // 2 MB (atomic path)
  float* partials = (float*)(ws + (size_t)(4u << 20));

  const size_t need32 = (size_t)(4u << 20) + 32 * XBYTES;   // 68 MB
  const size_t need16 = (size_t)(4u << 20) + 16 * XBYTES;   // 36 MB

  hipMemsetAsync(out, 0, sizeof(float) * out_size, stream);
  if (ws_size >= need32) {
    // 512 blocks (16 mtiles x 32 ksp) -> 2 blocks/CU, disjoint K slabs.
    gemm_bf16_splitk<<<dim3(MTILES * 32), dim3(512), 0, stream>>>(A, W, partials, 31, 5, 0);
    loss_kernel<<<dim3(M_DIM), dim3(256), 0, stream>>>(partials, 32, cls_w, nodes, codes, lens, out);
  } else if (ws_size >= need16) {
    gemm_bf16_splitk<<<dim3(MTILES * 16), dim3(512), 0, stream>>>(A, W, partials, 15, 4, 0);
    loss_kernel<<<dim3(M_DIM), dim3(256), 0, stream>>>(partials, 16, cls_w, nodes, codes, lens, out);
  } else {
    hipMemsetAsync(x, 0, XBYTES, stream);
    gemm_bf16_splitk<<<dim3(MTILES * 16), dim3(512), 0, stream>>>(A, W, x, 15, 4, 1);
    loss_kernel<<<dim3(M_DIM), dim3(256), 0, stream>>>(x, 1, cls_w, nodes, codes, lens, out);
  }
}

// Round 12
// 174.628 us; speedup vs baseline: 1.2304x; 1.2304x over previous
//
#include <hip/hip_runtime.h>
#include <hip/hip_bf16.h>

// Problem constants
#define M_DIM 2048
#define K_DIM 50000
#define N_DIM 256
#define L_PATH 32
// GEMM tiling: BM=256 halves the step count (49->25) to amortize per-step
// fixed overhead (barrier rendezvous + phase serialization), which R7-R11
// localized as the residual. LDS = 128KB, 1 block/CU, grid 256 = 8m x 32k.
#define BMt 256
#define BNt 256
#define BKt 64
#define TOTAL_KSTEPS 782      // ceil(50000/64)
#define KSPLIT 32
#define MTILES 8              // 2048/256

typedef __bf16 bf16x8 __attribute__((ext_vector_type(8)));
typedef __bf16 bf16x4 __attribute__((ext_vector_type(4)));
typedef float f32x4 __attribute__((ext_vector_type(4)));
typedef float fx4 __attribute__((ext_vector_type(4)));

// x = A (2048x50000) * W^T (W is 256x50000), split-K=32. bf16 MFMA, fp32 acc.
// R7-proven single-barrier counted-vmcnt loop, pack-FIRST ordering so the 64
// stage VGPRs die before fragments go live (peak live ~104 < the 128-VGPR
// allocator cap; R3/R4/R6 showed 2 live sets spill 548MB scratch).
// Per step: pack(p^1)[waits t+1 loads]; issue(t+2); compute(p); lgkm; barrier.
__global__ __launch_bounds__(512)
void gemm_bf16_splitk(const float* __restrict__ A, const float* __restrict__ W,
                      float* __restrict__ outp, int use_atomic)
{
  // Swizzled bf16 LDS tiles: (row, col) at row*BKt + XOR on 8-col/16B granule
  __shared__ __align__(16) unsigned short sA[2][BMt * BKt];   // 2 x 32 KB
  __shared__ __align__(16) unsigned short sW[2][BNt * BKt];   // 2 x 32 KB

  // XCD affinity: blocks sharing ksp (-> same W slab) land on one XCD.
  int bid = blockIdx.x;                       // 256 blocks
  int ksp = (bid & 7) * 4 + ((bid >> 3) & 3); // constant per bid%8 class
  int mtile = bid >> 5;

  int m0 = mtile * BMt;
  int s0 = (TOTAL_KSTEPS * ksp) >> 5;         // balanced ranges (~24-25 steps)
  int s1 = (TOTAL_KSTEPS * (ksp + 1)) >> 5;

  int tid = threadIdx.x;
  int wid = tid >> 6, lane = tid & 63;
  int wm = wid >> 2, wn = wid & 3;            // wave grid 2 x 4, wave tile 128x64
  int l15 = lane & 15, l4 = lane >> 4;

  // Coalesced staging: 16 lanes x 16B cover one 64-col row chunk (256 B).
  int rowt = tid >> 4;   // 0..31
  int chk  = tid & 15;   // 16B chunk (4 fp32 cols)
  const float* Ab = A + (size_t)(m0 + rowt) * K_DIM + chk * 4;
  const float* Wb = W + (size_t)rowt * K_DIM + chk * 4;

  int offA[8], offW[8];
#pragma unroll
  for (int i = 0; i < 8; ++i) {
    int r = i * 32 + rowt;
    int o = r * BKt + ((((chk >> 1) ^ (r & 7)) << 3) + (chk & 1) * 4);
    offA[i] = o; offW[i] = o;
  }

  // SINGLE stage set: 16 x fx4 = 64 VGPR, dead after pack (pack-first order).
  fx4 ra[8], rw[8];

  auto issue = [&](int s) {
    size_t kb = (size_t)s * BKt;
    const float* ap = Ab + kb;
    const float* wp = Wb + kb;
    int k = s * BKt + chk * 4;
    if (k + 4 <= K_DIM) {
#pragma unroll
      for (int i = 0; i < 8; ++i) ra[i] = *reinterpret_cast<const fx4*>(ap + (size_t)i * 32 * K_DIM);
#pragma unroll
      for (int i = 0; i < 8; ++i) rw[i] = *reinterpret_cast<const fx4*>(wp + (size_t)i * 32 * K_DIM);
    } else {
#pragma unroll
      for (int i = 0; i < 8; ++i) {
        fx4 f;
#pragma unroll
        for (int e = 0; e < 4; ++e) f[e] = (k + e < K_DIM) ? ap[(size_t)i * 32 * K_DIM + e] : 0.f;
        ra[i] = f;
      }
#pragma unroll
      for (int i = 0; i < 8; ++i) {
        fx4 f;
#pragma unroll
        for (int e = 0; e < 4; ++e) f[e] = (k + e < K_DIM) ? wp[(size_t)i * 32 * K_DIM + e] : 0.f;
        rw[i] = f;
      }
    }
  };

  // fp32 -> bf16 casts (v_cvt_pk_bf16_f32, RTNE). vmcnt here waits only the
  // staged tile's loads (nothing newer is outstanding at pack time).
  auto pack = [&](int p) {
#pragma unroll
    for (int i = 0; i < 8; ++i) {
      bf16x4 h;
      h[0] = (__bf16)ra[i][0]; h[1] = (__bf16)ra[i][1];
      h[2] = (__bf16)ra[i][2]; h[3] = (__bf16)ra[i][3];
      *reinterpret_cast<bf16x4*>(&sA[p][offA[i]]) = h;
    }
#pragma unroll
    for (int i = 0; i < 8; ++i) {
      bf16x4 h;
      h[0] = (__bf16)rw[i][0]; h[1] = (__bf16)rw[i][1];
      h[2] = (__bf16)rw[i][2]; h[3] = (__bf16)rw[i][3];
      *reinterpret_cast<bf16x4*>(&sW[p][offW[i]]) = h;
    }
  };

  f32x4 acc[8][4] = {};   // 128 accumulator regs (AGPR-side of unified file)

  // B-fragments resident (16 VGPR), A-fragments streamed per-mf (4 VGPR):
  // keeps peak arch-VGPR ~104.
  auto compute = [&](int p) {
#pragma unroll
    for (int kk = 0; kk < 2; ++kk) {
      int c = kk * 32 + l4 * 8;
      bf16x8 bfr[4];
#pragma unroll
      for (int nf = 0; nf < 4; ++nf) {
        int r = wn * 64 + nf * 16 + l15;
        bfr[nf] = *reinterpret_cast<const bf16x8*>(&sW[p][r * BKt + (c ^ ((r & 7) << 3))]);
      }
#pragma unroll
      for (int mf = 0; mf < 8; ++mf) {
        int r = wm * 128 + mf * 16 + l15;
        bf16x8 afr = *reinterpret_cast<const bf16x8*>(&sA[p][r * BKt + (c ^ ((r & 7) << 3))]);
#pragma unroll
        for (int nf = 0; nf < 4; ++nf)
          acc[mf][nf] = __builtin_amdgcn_mfma_f32_16x16x32_bf16(afr, bfr[nf], acc[mf][nf], 0, 0, 0);
      }
    }
  };

  // Prologue: tile s0 staged to LDS[0]; tile s0+1's loads left in flight.
  issue(s0);
  pack(0);
  if (s0 + 1 < s1) issue(s0 + 1);
  asm volatile("s_waitcnt lgkmcnt(0)" ::: "memory");
  __builtin_amdgcn_s_barrier();

  int p = 0;
  for (int t = s0; t < s1; ++t) {
    if (t + 1 < s1) {
      pack(p ^ 1);                   // buffer p^1: readers finished before the
                                     // barrier we just crossed; vmcnt waits
                                     // only tile t+1's loads (1 step old)
      if (t + 2 < s1) issue(t + 2);  // stays in flight across the barrier
    }
    compute(p);
    if (t + 1 < s1) {
      asm volatile("s_waitcnt lgkmcnt(0)" ::: "memory");
      __builtin_amdgcn_s_barrier();  // publish pack(p^1)
    }
    p ^= 1;
  }

  // epilogue: C/D layout col = lane&15, row = (lane>>4)*4 + j
  if (use_atomic) {
#pragma unroll
    for (int mf = 0; mf < 8; ++mf)
#pragma unroll
      for (int nf = 0; nf < 4; ++nf)
#pragma unroll
        for (int j = 0; j < 4; ++j) {
          int row = m0 + wm * 128 + mf * 16 + l4 * 4 + j;
          int col = wn * 64 + nf * 16 + l15;
          atomicAdd(&outp[(size_t)row * N_DIM + col], acc[mf][nf][j]);
        }
  } else {
    float* part = outp + (size_t)ksp * (M_DIM * N_DIM);
#pragma unroll
    for (int mf = 0; mf < 8; ++mf)
#pragma unroll
      for (int nf = 0; nf < 4; ++nf)
#pragma unroll
        for (int j = 0; j < 4; ++j) {
          int row = m0 + wm * 128 + mf * 16 + l4 * 4 + j;
          int col = wn * 64 + nf * 16 + l15;
          part[(size_t)row * N_DIM + col] = acc[mf][nf][j];
        }
  }
}

// ---------------------------------------------------------------------------
// One block per sample: reduce split-K partials, gather path vecs, dot, BCE,
// atomically accumulate batch mean into out[0] (memset to 0 beforehand).
__global__ __launch_bounds__(256)
void loss_kernel(const float* __restrict__ part, int nparts,
                 const float* __restrict__ cls_w,
                 const int* __restrict__ nodes, const int* __restrict__ codes,
                 const int* __restrict__ lens, float* __restrict__ out)
{
  int i = blockIdx.x;
  int tid = threadIdx.x;
  __shared__ float s_x[N_DIM];
  {
    float s = 0.f;
    for (int k = 0; k < nparts; ++k)
      s += part[(size_t)k * (M_DIM * N_DIM) + (size_t)i * N_DIM + tid];
    s_x[tid] = s;
  }
  __syncthreads();

  int wid = tid >> 6, lane = tid & 63;
  __shared__ float s_logit[L_PATH];
  fx4 xv = *reinterpret_cast<const fx4*>(&s_x[lane * 4]);
#pragma unroll
  for (int j = 0; j < 8; ++j) {
    int pos = wid * 8 + j;
    int node = nodes[i * L_PATH + pos];
    fx4 cv = *reinterpret_cast<const fx4*>(&cls_w[(size_t)node * N_DIM + lane * 4]);
    float d = xv[0] * cv[0] + xv[1] * cv[1] + xv[2] * cv[2] + xv[3] * cv[3];
#pragma unroll
    for (int s = 32; s > 0; s >>= 1) d += __shfl_xor(d, s);
    if (lane == 0) s_logit[pos] = d;
  }
  __syncthreads();
  if (wid == 0) {
    int len = lens[i];
    int lenc = len < 1 ? 1 : len;
    float v = 0.f;
    if (lane < L_PATH && lane < lenc) {
      float z = s_logit[lane];
      float y = (float)codes[i * L_PATH + lane];
      v = fmaxf(z, 0.f) - z * y + log1pf(expf(-fabsf(z)));
    }
#pragma unroll
    for (int s = 32; s > 0; s >>= 1) v += __shfl_xor(v, s);
    if (lane == 0) atomicAdd(out, v / (float)lenc * (1.0f / (float)M_DIM));
  }
}

extern "C" void kernel_launch(void* const* d_in, const int* in_sizes, int n_in,
                              void* d_out, int out_size, void* d_ws, size_t ws_size,
                              hipStream_t stream) {
  const float* A     = (const float*)d_in[0];   // inputs_vector [2048, 50000]
  const float* W     = (const float*)d_in[1];   // W [256, 50000]
  const float* cls_w = (const float*)d_in[2];   // [49999, 256]
  const int* nodes   = (const int*)d_in[3];     // [2048, 32]
  const int* codes   = (const int*)d_in[4];     // [2048, 32]
  const int* lens    = (const int*)d_in[5];     // [2048]
  float* out = (float*)d_out;

  char* ws = (char*)d_ws;
  const size_t XBYTES = (size_t)M_DIM * N_DIM * sizeof(float);   // 2 MB
  float* x        = (float*)(ws + (size_t)(64u << 10));          // 2 MB (atomic path)
  float* partials = (float*)(ws + (size_t)(4u << 20));           // KSPLIT * 2 MB

  const size_t need = (size_t)(4u << 20) + (size_t)KSPLIT * XBYTES;   // 68 MB

  hipMemsetAsync(out, 0, sizeof(float) * out_size, stream);
  if (ws_size >= need) {
    gemm_bf16_splitk<<<dim3(MTILES * KSPLIT), dim3(512), 0, stream>>>(A, W, partials, 0);
    loss_kernel<<<dim3(M_DIM), dim3(256), 0, stream>>>(partials, KSPLIT, cls_w, nodes, codes, lens, out);
  } else {
    hipMemsetAsync(x, 0, XBYTES, stream);
    gemm_bf16_splitk<<<dim3(MTILES * KSPLIT), dim3(512), 0, stream>>>(A, W, x, 1);
    loss_kernel<<<dim3(M_DIM), dim3(256), 0, stream>>>(x, 1, cls_w, nodes, codes, lens, out);
  }
}